// Round 9
// baseline (560.672 us; speedup 1.0000x reference)
//
#include <hip/hip_runtime.h>
#include <math.h>

// Problem constants (reference: B,N,M,C = 4,4096,4096,256)
#define BB 4
#define BN 4096          // N == M == 4096
#define CC 256
constexpr float T2      = 0.04f;                     // DIST_THRESH^2
constexpr float INV_EPS = (float)(1.0 / 0.01000001); // 1/(EPSILON + 1e-8)

typedef __attribute__((ext_vector_type(8)))  short bf16x8;
typedef __attribute__((ext_vector_type(16))) float f32x16;

__device__ __forceinline__ int cell_of(float x, float y) {
  int cx = (int)(x * 5.0f); cx = cx < 0 ? 0 : (cx > 4 ? 4 : cx);
  int cy = (int)(y * 5.0f); cy = cy < 0 ? 0 : (cy > 4 ? 4 : cy);
  return cy * 5 + cx;
}

// async global->LDS DMA: LDS dest = wave-uniform base + lane*size.
__device__ __forceinline__ void dma16(const void* g, void* l) {
  __builtin_amdgcn_global_load_lds(
      (const __attribute__((address_space(1))) void*)g,
      (__attribute__((address_space(3))) void*)l, 16, 0, 0);
}
__device__ __forceinline__ void dma4(const void* g, void* l) {
  __builtin_amdgcn_global_load_lds(
      (const __attribute__((address_space(1))) void*)g,
      (__attribute__((address_space(3))) void*)l, 4, 0, 0);
}

// ------------------------------------------------- fused binning (8 blk) ----
__global__ __launch_bounds__(256) void k_bin(
    const float* __restrict__ tlocs, const float* __restrict__ slocs,
    const int* __restrict__ tmask, const int* __restrict__ smask,
    int* __restrict__ Zc,
    int* __restrict__ starts_t, int* __restrict__ starts_s,
    int* __restrict__ perm_t, int* __restrict__ perm_s,
    float4* __restrict__ t_sorted, float4* __restrict__ s_sorted) {
  const int which = blockIdx.x & 1, b = blockIdx.x >> 1;   // grid = 2*B
  const float* locs = which ? slocs : tlocs;
  const int*   mask = which ? smask : tmask;
  int* starts       = which ? starts_s : starts_t;
  int* perm         = which ? perm_s : perm_t;
  float4* pack      = which ? s_sorted : t_sorted;
  const int tid = threadIdx.x;
  if (blockIdx.x == 0) Zc[tid] = 0;                        // 256 ints = 1 KB
  __shared__ int cnt[25];
  __shared__ int st[26];
  __shared__ int cur[25];
  if (tid < 25) cnt[tid] = 0;
  __syncthreads();
  for (int i = tid; i < BN; i += 256)
    atomicAdd(&cnt[cell_of(locs[(b * BN + i) * 2], locs[(b * BN + i) * 2 + 1])], 1);
  __syncthreads();
  if (tid == 0) {
    int acc = 0;
    for (int c = 0; c < 25; c++) { st[c] = acc; acc += cnt[c]; }
    st[25] = acc;                                          // == 4096
  }
  __syncthreads();
  if (tid < 25) cur[tid] = st[tid];
  if (tid < 26) starts[b * 32 + tid] = st[tid];
  __syncthreads();
  for (int i = tid; i < BN; i += 256) {
    float x = locs[(b * BN + i) * 2], y = locs[(b * BN + i) * 2 + 1];
    int pos = atomicAdd(&cur[cell_of(x, y)], 1);
    perm[b * BN + pos] = i;
    pack[b * BN + pos] = make_float4(x, y, 0.f, mask[b * BN + i] ? 1.f : 0.f);
  }
}

// -------------------------------------------- feats pre-pack (1024 blk) -----
// fB[b][blk][ch][sl'] u32 = (bf16hi<<16 | bf16lo), sl' = sl ^ (((ch>>1)&3)<<2).
__global__ __launch_bounds__(256) void k_pack(
    const float* __restrict__ feats, const int* __restrict__ perm_s,
    unsigned* __restrict__ fB) {
  const int b   = blockIdx.x >> 8;
  const int blk = blockIdx.x & 255;
  const int tid = threadIdx.x;
  __shared__ float fs[16][260];
  __shared__ int   sidx[16];
  if (tid < 16) sidx[tid] = perm_s[b * BN + blk * 16 + tid];
  __syncthreads();
  #pragma unroll
  for (int q = 0; q < 4; q++) {                    // coalesced row reads
    int idx = q * 256 + tid;
    int r = idx >> 6, c4 = idx & 63;
    float4 v = ((const float4*)feats)[(((b << 12) + sidx[r]) << 6) + c4];
    fs[r][c4 * 4 + 0] = v.x; fs[r][c4 * 4 + 1] = v.y;
    fs[r][c4 * 4 + 2] = v.z; fs[r][c4 * 4 + 3] = v.w;
  }
  __syncthreads();
  const int ch = tid;
  unsigned* dst = fB + ((((size_t)b << 8) + blk) << 12) + ch * 16;
  unsigned pk[16];
  #pragma unroll
  for (int sl = 0; sl < 16; sl++) {
    float f = fs[sl][ch];
    unsigned fb = __float_as_uint(f);
    unsigned hb = fb & 0xFFFF0000u;
    float lo = f - __uint_as_float(hb);
    pk[sl ^ (((ch >> 1) & 3) << 2)] = hb | (__float_as_uint(lo) >> 16);
  }
  #pragma unroll
  for (int q = 0; q < 4; q++)
    ((uint4*)dst)[q] = make_uint4(pk[q*4], pk[q*4+1], pk[q*4+2], pk[q*4+3]);
}

// ------------------------------------------------------ sparse Sinkhorn -----
// r4-verified; see prior rounds for the plain-sum / Z-leak argument.
__global__ __launch_bounds__(256) void k_sink(const float4* __restrict__ opp,
                                              float4* __restrict__ own,
                                              const int* __restrict__ opp_starts,
                                              const int* __restrict__ Zin,
                                              int* __restrict__ Zout,
                                              int zero_invalid) {
  const int wv   = threadIdx.x >> 6;
  const int lane = threadIdx.x & 63;
  const int rowb = blockIdx.x * 16 + wv * 4;
  const int b    = rowb >> 12;
  float4 me[4];
  float  s[4] = {0.f, 0.f, 0.f, 0.f};
  int ryLo = 5, ryHi = -1, rxLo = 5, rxHi = -1;
  #pragma unroll
  for (int i = 0; i < 4; i++) {
    me[i] = own[rowb + i];
    if (me[i].w != 0.f) {
      int cell = cell_of(me[i].x, me[i].y);
      int cy = cell / 5, cx = cell % 5;
      ryLo = min(ryLo, max(cy - 1, 0)); ryHi = max(ryHi, min(cy + 1, 4));
      rxLo = min(rxLo, max(cx - 1, 0)); rxHi = max(rxHi, min(cx + 1, 4));
    }
  }
  for (int ry = ryLo; ry <= ryHi; ry++) {
    const int r0 = opp_starts[b * 32 + ry * 5 + rxLo];
    const int r1 = opp_starts[b * 32 + ry * 5 + rxHi + 1];
    for (int j = r0 + lane; j < r1; j += 64) {
      float4 o = opp[b * BN + j];
      #pragma unroll
      for (int i = 0; i < 4; i++) {
        float dx = me[i].x - o.x, dy = me[i].y - o.y;
        float d2 = fmaf(dx, dx, dy * dy);
        bool  c  = (d2 < T2) && (o.w != 0.f) && (me[i].w != 0.f);
        float t  = c ? fmaf(d2, -INV_EPS, o.z) : -3e30f;
        s[i] += __expf(t);
      }
    }
  }
  #pragma unroll
  for (int i = 0; i < 4; i++)
    for (int off = 32; off > 0; off >>= 1) s[i] += __shfl_xor(s[i], off);
  if (lane == 0) {
    const float Zf = (float)Zin[b];
    #pragma unroll
    for (int i = 0; i < 4; i++) {
      float ss  = s[i] + Zf;
      float val = (ss > 0.f) ? -logf(ss) : 1.0e9f;
      if (zero_invalid && me[i].w == 0.f) val = 0.f;
      own[rowb + i] = make_float4(me[i].x, me[i].y, val, me[i].w);
      if (val == 1.0e9f) atomicAdd(&Zout[b], 1);
    }
  }
}

// ------------------------------------------------- sparse attn @ feats ------
// MFMA v3: counted-vmcnt depth-2 pipeline (T3/T4). All loop VMEM is DMA:
// per slot each wave issues EXACTLY 5 global_load_lds (4x fB-tile 16B +
// 1x s_sorted slab 4B -> 256B), triple-buffered (BUFU u32 each). Round r:
//   s_waitcnt vmcnt(5)   // slot r landed (FIFO); slot r+1 still in flight
//   s_barrier; sched_barrier
//   issue slot r+2 (tile index clamped to last -> count stays uniform)
//   B build (attn) from s-slab in LDS (broadcast b128 reads), straight into
//   mfma_f32_32x32x16_bf16 B-layout regs; A-frags via swizzled ds_read_b128;
//   3-term hi/lo MFMA (AhBh+AhBl+AlBh).
// After loop: vmcnt(0) + barrier before the Dl epilogue reuses the pool.
#define MAXCH 12    // 12*32 = 384 targets/cell upper bound
#define BUFU  4160  // per-buffer u32: 4096 fB tile + 64 s-slab

__global__ __launch_bounds__(256) void k_out(
    const unsigned* __restrict__ fB, const float4* __restrict__ t_sorted,
    const float4* __restrict__ s_sorted, const int* __restrict__ perm_t,
    const int* __restrict__ starts_t, const int* __restrict__ starts_s,
    float* __restrict__ out) {
  const int b = blockIdx.z;
  const int cell = blockIdx.y / 3, rsel = blockIdx.y % 3;
  const int cy = cell / 5, cx = cell % 5;
  const int ry = cy + rsel - 1;
  if (ry < 0 || ry > 4) return;                            // uniform early-exit
  const int t0 = starts_t[b * 32 + cell], t1 = starts_t[b * 32 + cell + 1];
  const int base = t0 + blockIdx.x * 32;
  if (base >= t1) return;
  const int rx0 = max(cx - 1, 0), rx1 = min(cx + 1, 4);
  const int s0 = starts_s[b * 32 + ry * 5 + rx0];
  const int s1 = starts_s[b * 32 + ry * 5 + rx1 + 1];
  if (s0 >= s1) return;
  const int nt = min(32, t1 - base);

  __shared__ __align__(16) unsigned pool[3 * BUFU];  // 48.75KB; Dl bounce overlays
  __shared__ float4 tL[32];
  __shared__ int    morg[32];

  const int tid  = threadIdx.x;
  const int lane = tid & 63;
  const int w    = tid >> 6;

  if (tid < 32) {
    if (tid < nt) {
      tL[tid]   = t_sorted[b * BN + base + tid];
      morg[tid] = perm_t[b * BN + base + tid];
    } else {
      tL[tid]   = make_float4(0.f, 0.f, 0.f, 0.f);         // tv=0 -> attn 0
      morg[tid] = 0;
    }
  }
  __syncthreads();

  const int kg = lane >> 5;                  // k-half: src kg*8 .. +7
  const int ln = lane & 31;                  // n(tm) for B/D, m(ch) for A
  const float4 t4a = tL[ln];                 // this lane's attn target row
  const int sB = b * BN;

  const int blk0 = s0 >> 4;
  const int nBlk = ((s1 + 15) >> 4) - blk0;

  // issue one DMA slot (5 per wave) for tile index t into buffer bufI
  const unsigned* fBb = fB + (((size_t)b) << 20);
  auto ISSUE = [&](int t, int bufI) {
    const unsigned* g = fBb + ((size_t)t << 12);
    unsigned* lb = pool + bufI * BUFU;
    #pragma unroll
    for (int q = 0; q < 4; q++)
      dma16(g + (w * 4 + q) * 256 + lane * 4, (void*)(lb + (w * 4 + q) * 256));
    dma4((const char*)s_sorted + ((size_t)(sB + t * 16) << 4) + lane * 4,
         (void*)(lb + 4096));
  };

  // ---- prologue: slots for rounds 0 and 1 ----------------------------------
  ISSUE(blk0, 0);
  ISSUE(blk0 + min(1, nBlk - 1), 1);

  f32x16 acc0, acc1;
  #pragma unroll
  for (int i = 0; i < 16; i++) { acc0[i] = 0.f; acc1[i] = 0.f; }

  int cur = 0;
  for (int r = 0; r < nBlk; r++) {
    asm volatile("s_waitcnt vmcnt(5)" ::: "memory");       // slot r landed
    __builtin_amdgcn_s_barrier();                          // all waves' slot r in
    __builtin_amdgcn_sched_barrier(0);
    ISSUE(blk0 + min(r + 2, nBlk - 1), cur == 0 ? 2 : cur - 1);  // slot r+2
    const unsigned* tile = pool + cur * BUFU;
    // ---- B fragments (attn) from the s-slab, straight into registers -------
    const int j0 = (blk0 + r) * 16 + kg * 8;
    unsigned ahv[8], alv[8];
    #pragma unroll
    for (int e = 0; e < 8; e++) {
      float4 s4 = *(const float4*)(tile + 4096 + (kg * 8 + e) * 4);
      int j = j0 + e;
      float dx = t4a.x - s4.x, dy = t4a.y - s4.y;
      float d2 = fmaf(dx, dx, dy * dy);
      bool  c  = (j >= s0) && (j < s1) && (d2 < T2) &&
                 (s4.w != 0.f) && (t4a.w != 0.f);
      float a  = c ? __expf(fmaf(d2, -INV_EPS, t4a.z + s4.z)) : 0.f;
      unsigned ab = __float_as_uint(a);
      unsigned hb = ab & 0xFFFF0000u;
      float alo = a - __uint_as_float(hb);
      ahv[e] = ab >> 16;
      alv[e] = __float_as_uint(alo) >> 16;
    }
    union { unsigned u[4]; bf16x8 v; } BH, BL;
    #pragma unroll
    for (int i = 0; i < 4; i++) {
      BH.u[i] = ahv[2*i] | (ahv[2*i+1] << 16);
      BL.u[i] = alv[2*i] | (alv[2*i+1] << 16);
    }
    // ---- A fragments + 6 MFMA ----------------------------------------------
    #pragma unroll
    for (int mt = 0; mt < 2; mt++) {
      const int chl = w * 64 + mt * 32 + ln;
      const int xv  = (chl >> 1) & 3;
      const int g0  = ((kg << 1) | 0) ^ xv;
      const int g1  = ((kg << 1) | 1) ^ xv;
      union { uint4 q[2]; unsigned u[8]; } A;
      A.q[0] = *(const uint4*)(tile + chl * 16 + g0 * 4);
      A.q[1] = *(const uint4*)(tile + chl * 16 + g1 * 4);
      union { unsigned u[4]; bf16x8 v; } AH, AL;
      #pragma unroll
      for (int i = 0; i < 4; i++) {
        AH.u[i] = (A.u[2*i] >> 16)     | (A.u[2*i+1] & 0xFFFF0000u);
        AL.u[i] = (A.u[2*i] & 0xFFFFu) | (A.u[2*i+1] << 16);
      }
      if (mt == 0) {
        acc0 = __builtin_amdgcn_mfma_f32_32x32x16_bf16(AH.v, BH.v, acc0, 0, 0, 0);
        acc0 = __builtin_amdgcn_mfma_f32_32x32x16_bf16(AH.v, BL.v, acc0, 0, 0, 0);
        acc0 = __builtin_amdgcn_mfma_f32_32x32x16_bf16(AL.v, BH.v, acc0, 0, 0, 0);
      } else {
        acc1 = __builtin_amdgcn_mfma_f32_32x32x16_bf16(AH.v, BH.v, acc1, 0, 0, 0);
        acc1 = __builtin_amdgcn_mfma_f32_32x32x16_bf16(AH.v, BL.v, acc1, 0, 0, 0);
        acc1 = __builtin_amdgcn_mfma_f32_32x32x16_bf16(AL.v, BH.v, acc1, 0, 0, 0);
      }
    }
    cur = (cur == 2) ? 0 : cur + 1;
  }

  // ---- epilogue: drain DMAs, D -> Dl[tm][ch] (stride 268) -> atomic flush --
  asm volatile("s_waitcnt vmcnt(0)" ::: "memory");         // clamped slots too
  __syncthreads();                           // all MAC reads of pool done
  float* Dl = (float*)pool;
  #pragma unroll
  for (int mt = 0; mt < 2; mt++) {
    #pragma unroll
    for (int rg = 0; rg < 4; rg++) {         // regs rg*4..+3 -> rows 8rg+4kg..+3
      int chb = w * 64 + mt * 32 + 8 * rg + 4 * kg;
      float4 v;
      if (mt == 0) v = make_float4(acc0[rg*4], acc0[rg*4+1], acc0[rg*4+2], acc0[rg*4+3]);
      else         v = make_float4(acc1[rg*4], acc1[rg*4+1], acc1[rg*4+2], acc1[rg*4+3]);
      *(float4*)&Dl[ln * 268 + chb] = v;
    }
  }
  __syncthreads();
  {
    const int tmg = tid >> 5, chg = tid & 31;
    #pragma unroll
    for (int i = 0; i < 4; i++) {
      int tm = tmg * 4 + i;
      if (tm < nt) {
        float* op = out + (((b << 12) + morg[tm]) << 8) + chg * 4;
        float4 d0 = *(float4*)&Dl[tm * 268 + chg * 4];
        float4 d1 = *(float4*)&Dl[tm * 268 + 128 + chg * 4];
        atomicAdd(op + 0, d0.x); atomicAdd(op + 1, d0.y);
        atomicAdd(op + 2, d0.z); atomicAdd(op + 3, d0.w);
        atomicAdd(op + 128, d1.x); atomicAdd(op + 129, d1.y);
        atomicAdd(op + 130, d1.z); atomicAdd(op + 131, d1.w);
      }
    }
  }
}

// ----------------------------------------------------------------- launch ---
extern "C" void kernel_launch(void* const* d_in, const int* in_sizes, int n_in,
                              void* d_out, int out_size, void* d_ws, size_t ws_size,
                              hipStream_t stream) {
  const float* feats = (const float*)d_in[0];   // [B,N,C] f32
  const float* slocs = (const float*)d_in[1];   // [B,N,2] f32
  const float* tlocs = (const float*)d_in[2];   // [B,M,2] f32
  const int*   smask = (const int*)d_in[3];     // [B,N] int32 (bool)
  const int*   tmask = (const int*)d_in[4];     // [B,M] int32 (bool)
  float* out = (float*)d_out;

  char* ws = (char*)d_ws;                       // ~660 KB + 16 MB fB
  int*    Zc       = (int*)(ws + 1024);         //   256 ints; slot 0 stays 0
  int*    starts_t = (int*)(ws + 2048);         //   512 B
  int*    starts_s = (int*)(ws + 2560);         //   512 B
  int*    perm_t   = (int*)(ws + 4096);         //   64 KB
  int*    perm_s   = (int*)(ws + 69632);        //   64 KB
  float4* s_sorted = (float4*)(ws + 135168);    //  256 KB (x,y,v,sv) cell-sorted
  float4* t_sorted = (float4*)(ws + 397312);    //  256 KB (x,y,u,tv) cell-sorted
  unsigned* fB     = (unsigned*)(ws + 663552);  // 16 MB packed feats tiles

  hipMemsetAsync(out, 0, (size_t)out_size * sizeof(float), stream);
  k_bin<<<8, 256, 0, stream>>>(tlocs, slocs, tmask, smask, Zc,
                               starts_t, starts_s, perm_t, perm_s,
                               t_sorted, s_sorted);
  k_pack<<<1024, 256, 0, stream>>>(feats, perm_s, fB);
  for (int it = 0; it < 3; it++) {
    k_sink<<<1024, 256, 0, stream>>>(s_sorted, t_sorted, starts_s,
                                     Zc + (it == 0 ? 0 : (2 * it) * 4),
                                     Zc + (2 * it + 1) * 4, 0);
    k_sink<<<1024, 256, 0, stream>>>(t_sorted, s_sorted, starts_t,
                                     Zc + (2 * it + 1) * 4,
                                     Zc + (2 * it + 2) * 4, 1);
  }
  k_out<<<dim3(MAXCH, 75, BB), 256, 0, stream>>>(fB, t_sorted, s_sorted,
                                                 perm_t, starts_t, starts_s,
                                                 out);
}

// Round 10
// 558.797 us; speedup vs baseline: 1.0034x; 1.0034x over previous
//
#include <hip/hip_runtime.h>
#include <math.h>

// Problem constants (reference: B,N,M,C = 4,4096,4096,256)
#define BB 4
#define BN 4096          // N == M == 4096
#define CC 256
constexpr float T2      = 0.04f;                     // DIST_THRESH^2
constexpr float INV_EPS = (float)(1.0 / 0.01000001); // 1/(EPSILON + 1e-8)

typedef __attribute__((ext_vector_type(8)))  short bf16x8;
typedef __attribute__((ext_vector_type(16))) float f32x16;

__device__ __forceinline__ int cell_of(float x, float y) {
  int cx = (int)(x * 5.0f); cx = cx < 0 ? 0 : (cx > 4 ? 4 : cx);
  int cy = (int)(y * 5.0f); cy = cy < 0 ? 0 : (cy > 4 ? 4 : cy);
  return cy * 5 + cx;
}

// async global->LDS DMA: LDS dest = wave-uniform base + lane*size.
__device__ __forceinline__ void dma16(const void* g, void* l) {
  __builtin_amdgcn_global_load_lds(
      (const __attribute__((address_space(1))) void*)g,
      (__attribute__((address_space(3))) void*)l, 16, 0, 0);
}
__device__ __forceinline__ void dma4(const void* g, void* l) {
  __builtin_amdgcn_global_load_lds(
      (const __attribute__((address_space(1))) void*)g,
      (__attribute__((address_space(3))) void*)l, 4, 0, 0);
}

// ------------------------------------------------- fused binning (8 blk) ----
__global__ __launch_bounds__(256) void k_bin(
    const float* __restrict__ tlocs, const float* __restrict__ slocs,
    const int* __restrict__ tmask, const int* __restrict__ smask,
    int* __restrict__ Zc,
    int* __restrict__ starts_t, int* __restrict__ starts_s,
    int* __restrict__ perm_t, int* __restrict__ perm_s,
    float4* __restrict__ t_sorted, float4* __restrict__ s_sorted) {
  const int which = blockIdx.x & 1, b = blockIdx.x >> 1;   // grid = 2*B
  const float* locs = which ? slocs : tlocs;
  const int*   mask = which ? smask : tmask;
  int* starts       = which ? starts_s : starts_t;
  int* perm         = which ? perm_s : perm_t;
  float4* pack      = which ? s_sorted : t_sorted;
  const int tid = threadIdx.x;
  if (blockIdx.x == 0) Zc[tid] = 0;                        // 256 ints = 1 KB
  __shared__ int cnt[25];
  __shared__ int st[26];
  __shared__ int cur[25];
  if (tid < 25) cnt[tid] = 0;
  __syncthreads();
  for (int i = tid; i < BN; i += 256)
    atomicAdd(&cnt[cell_of(locs[(b * BN + i) * 2], locs[(b * BN + i) * 2 + 1])], 1);
  __syncthreads();
  if (tid == 0) {
    int acc = 0;
    for (int c = 0; c < 25; c++) { st[c] = acc; acc += cnt[c]; }
    st[25] = acc;                                          // == 4096
  }
  __syncthreads();
  if (tid < 25) cur[tid] = st[tid];
  if (tid < 26) starts[b * 32 + tid] = st[tid];
  __syncthreads();
  for (int i = tid; i < BN; i += 256) {
    float x = locs[(b * BN + i) * 2], y = locs[(b * BN + i) * 2 + 1];
    int pos = atomicAdd(&cur[cell_of(x, y)], 1);
    perm[b * BN + pos] = i;
    pack[b * BN + pos] = make_float4(x, y, 0.f, mask[b * BN + i] ? 1.f : 0.f);
  }
}

// -------------------------------------------- feats pre-pack (1024 blk) -----
// fB[b][blk][ch][sl'] u32 = (bf16hi<<16 | bf16lo), sl' = sl ^ (((ch>>1)&3)<<2).
__global__ __launch_bounds__(256) void k_pack(
    const float* __restrict__ feats, const int* __restrict__ perm_s,
    unsigned* __restrict__ fB) {
  const int b   = blockIdx.x >> 8;
  const int blk = blockIdx.x & 255;
  const int tid = threadIdx.x;
  __shared__ float fs[16][260];
  __shared__ int   sidx[16];
  if (tid < 16) sidx[tid] = perm_s[b * BN + blk * 16 + tid];
  __syncthreads();
  #pragma unroll
  for (int q = 0; q < 4; q++) {                    // coalesced row reads
    int idx = q * 256 + tid;
    int r = idx >> 6, c4 = idx & 63;
    float4 v = ((const float4*)feats)[(((b << 12) + sidx[r]) << 6) + c4];
    fs[r][c4 * 4 + 0] = v.x; fs[r][c4 * 4 + 1] = v.y;
    fs[r][c4 * 4 + 2] = v.z; fs[r][c4 * 4 + 3] = v.w;
  }
  __syncthreads();
  const int ch = tid;
  unsigned* dst = fB + ((((size_t)b << 8) + blk) << 12) + ch * 16;
  unsigned pk[16];
  #pragma unroll
  for (int sl = 0; sl < 16; sl++) {
    float f = fs[sl][ch];
    unsigned fb = __float_as_uint(f);
    unsigned hb = fb & 0xFFFF0000u;
    float lo = f - __uint_as_float(hb);
    pk[sl ^ (((ch >> 1) & 3) << 2)] = hb | (__float_as_uint(lo) >> 16);
  }
  #pragma unroll
  for (int q = 0; q < 4; q++)
    ((uint4*)dst)[q] = make_uint4(pk[q*4], pk[q*4+1], pk[q*4+2], pk[q*4+3]);
}

// ------------------------------------------------------ sparse Sinkhorn -----
// r4-verified; see prior rounds for the plain-sum / Z-leak argument.
__global__ __launch_bounds__(256) void k_sink(const float4* __restrict__ opp,
                                              float4* __restrict__ own,
                                              const int* __restrict__ opp_starts,
                                              const int* __restrict__ Zin,
                                              int* __restrict__ Zout,
                                              int zero_invalid) {
  const int wv   = threadIdx.x >> 6;
  const int lane = threadIdx.x & 63;
  const int rowb = blockIdx.x * 16 + wv * 4;
  const int b    = rowb >> 12;
  float4 me[4];
  float  s[4] = {0.f, 0.f, 0.f, 0.f};
  int ryLo = 5, ryHi = -1, rxLo = 5, rxHi = -1;
  #pragma unroll
  for (int i = 0; i < 4; i++) {
    me[i] = own[rowb + i];
    if (me[i].w != 0.f) {
      int cell = cell_of(me[i].x, me[i].y);
      int cy = cell / 5, cx = cell % 5;
      ryLo = min(ryLo, max(cy - 1, 0)); ryHi = max(ryHi, min(cy + 1, 4));
      rxLo = min(rxLo, max(cx - 1, 0)); rxHi = max(rxHi, min(cx + 1, 4));
    }
  }
  for (int ry = ryLo; ry <= ryHi; ry++) {
    const int r0 = opp_starts[b * 32 + ry * 5 + rxLo];
    const int r1 = opp_starts[b * 32 + ry * 5 + rxHi + 1];
    for (int j = r0 + lane; j < r1; j += 64) {
      float4 o = opp[b * BN + j];
      #pragma unroll
      for (int i = 0; i < 4; i++) {
        float dx = me[i].x - o.x, dy = me[i].y - o.y;
        float d2 = fmaf(dx, dx, dy * dy);
        bool  c  = (d2 < T2) && (o.w != 0.f) && (me[i].w != 0.f);
        float t  = c ? fmaf(d2, -INV_EPS, o.z) : -3e30f;
        s[i] += __expf(t);
      }
    }
  }
  #pragma unroll
  for (int i = 0; i < 4; i++)
    for (int off = 32; off > 0; off >>= 1) s[i] += __shfl_xor(s[i], off);
  if (lane == 0) {
    const float Zf = (float)Zin[b];
    #pragma unroll
    for (int i = 0; i < 4; i++) {
      float ss  = s[i] + Zf;
      float val = (ss > 0.f) ? -logf(ss) : 1.0e9f;
      if (zero_invalid && me[i].w == 0.f) val = 0.f;
      own[rowb + i] = make_float4(me[i].x, me[i].y, val, me[i].w);
      if (val == 1.0e9f) atomicAdd(&Zout[b], 1);
    }
  }
}

// ------------------------------------------------- sparse attn @ feats ------
// MFMA v4: BARRIER-FREE per-wave pipelines. Data-flow audit: wave w's DMA
// stages exactly the tile channels [w*64, w*64+64) that wave w alone
// consumes; the only shared LDS was the 256B s-slab -> now PRIVATE per wave
// (+w*64 u32). So the in-loop s_barrier synchronized nothing: removed.
// Each wave runs its own depth-2 counted-vmcnt pipeline (vmcnt is per-wave):
//   vmcnt(5) -> own slot r landed; sched_barrier(0) (rule #18);
//   issue slot r+2 (5 DMAs: 4x tile-16B + 1x slab-4B); B build from own
//   slab; A frags via swizzled ds_read_b128; 6 MFMA (3-term hi/lo).
// Cross-wave syncs remain ONLY where real deps exist: after tL staging and
// before the Dl epilogue overlays the pool (each wave drains vmcnt(0) first).
#define MAXCH 12    // 12*32 = 384 targets/cell upper bound
#define BUFU  4352  // per-buffer u32: 4096 fB tile + 4 x 64 private s-slabs

__global__ __launch_bounds__(256) void k_out(
    const unsigned* __restrict__ fB, const float4* __restrict__ t_sorted,
    const float4* __restrict__ s_sorted, const int* __restrict__ perm_t,
    const int* __restrict__ starts_t, const int* __restrict__ starts_s,
    float* __restrict__ out) {
  const int b = blockIdx.z;
  const int cell = blockIdx.y / 3, rsel = blockIdx.y % 3;
  const int cy = cell / 5, cx = cell % 5;
  const int ry = cy + rsel - 1;
  if (ry < 0 || ry > 4) return;                            // uniform early-exit
  const int t0 = starts_t[b * 32 + cell], t1 = starts_t[b * 32 + cell + 1];
  const int base = t0 + blockIdx.x * 32;
  if (base >= t1) return;
  const int rx0 = max(cx - 1, 0), rx1 = min(cx + 1, 4);
  const int s0 = starts_s[b * 32 + ry * 5 + rx0];
  const int s1 = starts_s[b * 32 + ry * 5 + rx1 + 1];
  if (s0 >= s1) return;
  const int nt = min(32, t1 - base);

  __shared__ __align__(16) unsigned pool[3 * BUFU];  // 52.2KB; Dl bounce overlays
  __shared__ float4 tL[32];
  __shared__ int    morg[32];

  const int tid  = threadIdx.x;
  const int lane = tid & 63;
  const int w    = tid >> 6;

  if (tid < 32) {
    if (tid < nt) {
      tL[tid]   = t_sorted[b * BN + base + tid];
      morg[tid] = perm_t[b * BN + base + tid];
    } else {
      tL[tid]   = make_float4(0.f, 0.f, 0.f, 0.f);         // tv=0 -> attn 0
      morg[tid] = 0;
    }
  }
  __syncthreads();

  const int kg = lane >> 5;                  // k-half: src kg*8 .. +7
  const int ln = lane & 31;                  // n(tm) for B/D, m(ch) for A
  const float4 t4a = tL[ln];                 // this lane's attn target row
  const int sB = b * BN;

  const int blk0 = s0 >> 4;
  const int nBlk = ((s1 + 15) >> 4) - blk0;

  // issue one DMA slot (5 per wave) for tile index t into buffer bufI.
  // wave w stages ONLY its own channels [w*64,w*64+64) + its private slab.
  const unsigned* fBb = fB + (((size_t)b) << 20);
  auto ISSUE = [&](int t, int bufI) {
    const unsigned* g = fBb + ((size_t)t << 12);
    unsigned* lb = pool + bufI * BUFU;
    #pragma unroll
    for (int q = 0; q < 4; q++)
      dma16(g + (w * 4 + q) * 256 + lane * 4, (void*)(lb + (w * 4 + q) * 256));
    dma4((const char*)s_sorted + ((size_t)(sB + t * 16) << 4) + lane * 4,
         (void*)(lb + 4096 + w * 64));
  };

  // ---- prologue: slots for rounds 0 and 1 ----------------------------------
  ISSUE(blk0, 0);
  ISSUE(blk0 + min(1, nBlk - 1), 1);

  f32x16 acc0, acc1;
  #pragma unroll
  for (int i = 0; i < 16; i++) { acc0[i] = 0.f; acc1[i] = 0.f; }

  int cur = 0;
  for (int r = 0; r < nBlk; r++) {
    asm volatile("s_waitcnt vmcnt(5)" ::: "memory");       // own slot r landed
    __builtin_amdgcn_sched_barrier(0);                     // rule #18 fence
    ISSUE(blk0 + min(r + 2, nBlk - 1), cur == 0 ? 2 : cur - 1);  // slot r+2
    const unsigned* tile = pool + cur * BUFU;
    // ---- B fragments (attn) from the PRIVATE s-slab ------------------------
    const int j0 = (blk0 + r) * 16 + kg * 8;
    unsigned ahv[8], alv[8];
    #pragma unroll
    for (int e = 0; e < 8; e++) {
      float4 s4 = *(const float4*)(tile + 4096 + w * 64 + (kg * 8 + e) * 4);
      int j = j0 + e;
      float dx = t4a.x - s4.x, dy = t4a.y - s4.y;
      float d2 = fmaf(dx, dx, dy * dy);
      bool  c  = (j >= s0) && (j < s1) && (d2 < T2) &&
                 (s4.w != 0.f) && (t4a.w != 0.f);
      float a  = c ? __expf(fmaf(d2, -INV_EPS, t4a.z + s4.z)) : 0.f;
      unsigned ab = __float_as_uint(a);
      unsigned hb = ab & 0xFFFF0000u;
      float alo = a - __uint_as_float(hb);
      ahv[e] = ab >> 16;
      alv[e] = __float_as_uint(alo) >> 16;
    }
    union { unsigned u[4]; bf16x8 v; } BH, BL;
    #pragma unroll
    for (int i = 0; i < 4; i++) {
      BH.u[i] = ahv[2*i] | (ahv[2*i+1] << 16);
      BL.u[i] = alv[2*i] | (alv[2*i+1] << 16);
    }
    // ---- A fragments + 6 MFMA ----------------------------------------------
    #pragma unroll
    for (int mt = 0; mt < 2; mt++) {
      const int chl = w * 64 + mt * 32 + ln;
      const int xv  = (chl >> 1) & 3;
      const int g0  = ((kg << 1) | 0) ^ xv;
      const int g1  = ((kg << 1) | 1) ^ xv;
      union { uint4 q[2]; unsigned u[8]; } A;
      A.q[0] = *(const uint4*)(tile + chl * 16 + g0 * 4);
      A.q[1] = *(const uint4*)(tile + chl * 16 + g1 * 4);
      union { unsigned u[4]; bf16x8 v; } AH, AL;
      #pragma unroll
      for (int i = 0; i < 4; i++) {
        AH.u[i] = (A.u[2*i] >> 16)     | (A.u[2*i+1] & 0xFFFF0000u);
        AL.u[i] = (A.u[2*i] & 0xFFFFu) | (A.u[2*i+1] << 16);
      }
      if (mt == 0) {
        acc0 = __builtin_amdgcn_mfma_f32_32x32x16_bf16(AH.v, BH.v, acc0, 0, 0, 0);
        acc0 = __builtin_amdgcn_mfma_f32_32x32x16_bf16(AH.v, BL.v, acc0, 0, 0, 0);
        acc0 = __builtin_amdgcn_mfma_f32_32x32x16_bf16(AL.v, BH.v, acc0, 0, 0, 0);
      } else {
        acc1 = __builtin_amdgcn_mfma_f32_32x32x16_bf16(AH.v, BH.v, acc1, 0, 0, 0);
        acc1 = __builtin_amdgcn_mfma_f32_32x32x16_bf16(AH.v, BL.v, acc1, 0, 0, 0);
        acc1 = __builtin_amdgcn_mfma_f32_32x32x16_bf16(AL.v, BH.v, acc1, 0, 0, 0);
      }
    }
    cur = (cur == 2) ? 0 : cur + 1;
  }

  // ---- epilogue: drain own DMAs, block-sync, Dl bounce, atomic flush -------
  asm volatile("s_waitcnt vmcnt(0)" ::: "memory");         // own in-flight DMAs
  __syncthreads();                           // all waves done with pool
  float* Dl = (float*)pool;
  #pragma unroll
  for (int mt = 0; mt < 2; mt++) {
    #pragma unroll
    for (int rg = 0; rg < 4; rg++) {         // regs rg*4..+3 -> rows 8rg+4kg..+3
      int chb = w * 64 + mt * 32 + 8 * rg + 4 * kg;
      float4 v;
      if (mt == 0) v = make_float4(acc0[rg*4], acc0[rg*4+1], acc0[rg*4+2], acc0[rg*4+3]);
      else         v = make_float4(acc1[rg*4], acc1[rg*4+1], acc1[rg*4+2], acc1[rg*4+3]);
      *(float4*)&Dl[ln * 268 + chb] = v;
    }
  }
  __syncthreads();
  {
    const int tmg = tid >> 5, chg = tid & 31;
    #pragma unroll
    for (int i = 0; i < 4; i++) {
      int tm = tmg * 4 + i;
      if (tm < nt) {
        float* op = out + (((b << 12) + morg[tm]) << 8) + chg * 4;
        float4 d0 = *(float4*)&Dl[tm * 268 + chg * 4];
        float4 d1 = *(float4*)&Dl[tm * 268 + 128 + chg * 4];
        atomicAdd(op + 0, d0.x); atomicAdd(op + 1, d0.y);
        atomicAdd(op + 2, d0.z); atomicAdd(op + 3, d0.w);
        atomicAdd(op + 128, d1.x); atomicAdd(op + 129, d1.y);
        atomicAdd(op + 130, d1.z); atomicAdd(op + 131, d1.w);
      }
    }
  }
}

// ----------------------------------------------------------------- launch ---
extern "C" void kernel_launch(void* const* d_in, const int* in_sizes, int n_in,
                              void* d_out, int out_size, void* d_ws, size_t ws_size,
                              hipStream_t stream) {
  const float* feats = (const float*)d_in[0];   // [B,N,C] f32
  const float* slocs = (const float*)d_in[1];   // [B,N,2] f32
  const float* tlocs = (const float*)d_in[2];   // [B,M,2] f32
  const int*   smask = (const int*)d_in[3];     // [B,N] int32 (bool)
  const int*   tmask = (const int*)d_in[4];     // [B,M] int32 (bool)
  float* out = (float*)d_out;

  char* ws = (char*)d_ws;                       // ~660 KB + 16 MB fB
  int*    Zc       = (int*)(ws + 1024);         //   256 ints; slot 0 stays 0
  int*    starts_t = (int*)(ws + 2048);         //   512 B
  int*    starts_s = (int*)(ws + 2560);         //   512 B
  int*    perm_t   = (int*)(ws + 4096);         //   64 KB
  int*    perm_s   = (int*)(ws + 69632);        //   64 KB
  float4* s_sorted = (float4*)(ws + 135168);    //  256 KB (x,y,v,sv) cell-sorted
  float4* t_sorted = (float4*)(ws + 397312);    //  256 KB (x,y,u,tv) cell-sorted
  unsigned* fB     = (unsigned*)(ws + 663552);  // 16 MB packed feats tiles

  hipMemsetAsync(out, 0, (size_t)out_size * sizeof(float), stream);
  k_bin<<<8, 256, 0, stream>>>(tlocs, slocs, tmask, smask, Zc,
                               starts_t, starts_s, perm_t, perm_s,
                               t_sorted, s_sorted);
  k_pack<<<1024, 256, 0, stream>>>(feats, perm_s, fB);
  for (int it = 0; it < 3; it++) {
    k_sink<<<1024, 256, 0, stream>>>(s_sorted, t_sorted, starts_s,
                                     Zc + (it == 0 ? 0 : (2 * it) * 4),
                                     Zc + (2 * it + 1) * 4, 0);
    k_sink<<<1024, 256, 0, stream>>>(t_sorted, s_sorted, starts_t,
                                     Zc + (2 * it + 1) * 4,
                                     Zc + (2 * it + 2) * 4, 1);
  }
  k_out<<<dim3(MAXCH, 75, BB), 256, 0, stream>>>(fB, t_sorted, s_sorted,
                                                 perm_t, starts_t, starts_s,
                                                 out);
}

// Round 11
// 552.891 us; speedup vs baseline: 1.0141x; 1.0107x over previous
//
#include <hip/hip_runtime.h>
#include <math.h>

// Problem constants (reference: B,N,M,C = 4,4096,4096,256)
#define BB 4
#define BN 4096          // N == M == 4096
#define CC 256
constexpr float T2      = 0.04f;                     // DIST_THRESH^2
constexpr float INV_EPS = (float)(1.0 / 0.01000001); // 1/(EPSILON + 1e-8)

typedef __attribute__((ext_vector_type(8)))  short bf16x8;
typedef __attribute__((ext_vector_type(16))) float f32x16;

__device__ __forceinline__ int cell_of(float x, float y) {
  int cx = (int)(x * 5.0f); cx = cx < 0 ? 0 : (cx > 4 ? 4 : cx);
  int cy = (int)(y * 5.0f); cy = cy < 0 ? 0 : (cy > 4 ? 4 : cy);
  return cy * 5 + cx;
}

// async global->LDS DMA: LDS dest = wave-uniform base + lane*size.
__device__ __forceinline__ void dma16(const void* g, void* l) {
  __builtin_amdgcn_global_load_lds(
      (const __attribute__((address_space(1))) void*)g,
      (__attribute__((address_space(3))) void*)l, 16, 0, 0);
}
__device__ __forceinline__ void dma4(const void* g, void* l) {
  __builtin_amdgcn_global_load_lds(
      (const __attribute__((address_space(1))) void*)g,
      (__attribute__((address_space(3))) void*)l, 4, 0, 0);
}

// ------------------------------------------------- fused binning (8 blk) ----
__global__ __launch_bounds__(256) void k_bin(
    const float* __restrict__ tlocs, const float* __restrict__ slocs,
    const int* __restrict__ tmask, const int* __restrict__ smask,
    int* __restrict__ Zc, int* __restrict__ qcnt,
    int* __restrict__ starts_t, int* __restrict__ starts_s,
    int* __restrict__ perm_t, int* __restrict__ perm_s,
    float4* __restrict__ t_sorted, float4* __restrict__ s_sorted) {
  const int which = blockIdx.x & 1, b = blockIdx.x >> 1;   // grid = 2*B
  const float* locs = which ? slocs : tlocs;
  const int*   mask = which ? smask : tmask;
  int* starts       = which ? starts_s : starts_t;
  int* perm         = which ? perm_s : perm_t;
  float4* pack      = which ? s_sorted : t_sorted;
  const int tid = threadIdx.x;
  if (blockIdx.x == 0) {
    Zc[tid] = 0;                                           // 256 ints = 1 KB
    if (tid == 0) qcnt[0] = 0;                             // k_out work queue
  }
  __shared__ int cnt[25];
  __shared__ int st[26];
  __shared__ int cur[25];
  if (tid < 25) cnt[tid] = 0;
  __syncthreads();
  for (int i = tid; i < BN; i += 256)
    atomicAdd(&cnt[cell_of(locs[(b * BN + i) * 2], locs[(b * BN + i) * 2 + 1])], 1);
  __syncthreads();
  if (tid == 0) {
    int acc = 0;
    for (int c = 0; c < 25; c++) { st[c] = acc; acc += cnt[c]; }
    st[25] = acc;                                          // == 4096
  }
  __syncthreads();
  if (tid < 25) cur[tid] = st[tid];
  if (tid < 26) starts[b * 32 + tid] = st[tid];
  __syncthreads();
  for (int i = tid; i < BN; i += 256) {
    float x = locs[(b * BN + i) * 2], y = locs[(b * BN + i) * 2 + 1];
    int pos = atomicAdd(&cur[cell_of(x, y)], 1);
    perm[b * BN + pos] = i;
    pack[b * BN + pos] = make_float4(x, y, 0.f, mask[b * BN + i] ? 1.f : 0.f);
  }
}

// -------------------------------------------- feats pre-pack (1024 blk) -----
// No-LDS rewrite: per sl, all 256 threads read feats[sidx[sl]][0..255] =
// one fully-coalesced 1KB row; pack in registers; store the [ch][sl'] tile.
// fB[b][blk][ch][sl'] u32 = (bf16hi<<16|bf16lo), sl' = sl ^ (((ch>>1)&3)<<2).
__global__ __launch_bounds__(256) void k_pack(
    const float* __restrict__ feats, const int* __restrict__ perm_s,
    unsigned* __restrict__ fB) {
  const int b   = blockIdx.x >> 8;
  const int blk = blockIdx.x & 255;
  const int tid = threadIdx.x;
  __shared__ int sidx[16];
  if (tid < 16) sidx[tid] = perm_s[b * BN + blk * 16 + tid];
  __syncthreads();
  const int ch = tid;
  unsigned pk[16];
  #pragma unroll
  for (int sl = 0; sl < 16; sl++) {
    float f = feats[((((size_t)(b << 12)) + sidx[sl]) << 8) + ch];
    unsigned fbt = __float_as_uint(f);
    unsigned hb  = fbt & 0xFFFF0000u;
    float lo = f - __uint_as_float(hb);
    pk[sl ^ (((ch >> 1) & 3) << 2)] = hb | (__float_as_uint(lo) >> 16);
  }
  unsigned* dst = fB + ((((size_t)b << 8) + blk) << 12) + ch * 16;
  #pragma unroll
  for (int q = 0; q < 4; q++)
    ((uint4*)dst)[q] = make_uint4(pk[q*4], pk[q*4+1], pk[q*4+2], pk[q*4+3]);
}

// ------------------------------------------------------ sparse Sinkhorn -----
// r4-verified; see prior rounds for the plain-sum / Z-leak argument.
__global__ __launch_bounds__(256) void k_sink(const float4* __restrict__ opp,
                                              float4* __restrict__ own,
                                              const int* __restrict__ opp_starts,
                                              const int* __restrict__ Zin,
                                              int* __restrict__ Zout,
                                              int zero_invalid) {
  const int wv   = threadIdx.x >> 6;
  const int lane = threadIdx.x & 63;
  const int rowb = blockIdx.x * 16 + wv * 4;
  const int b    = rowb >> 12;
  float4 me[4];
  float  s[4] = {0.f, 0.f, 0.f, 0.f};
  int ryLo = 5, ryHi = -1, rxLo = 5, rxHi = -1;
  #pragma unroll
  for (int i = 0; i < 4; i++) {
    me[i] = own[rowb + i];
    if (me[i].w != 0.f) {
      int cell = cell_of(me[i].x, me[i].y);
      int cy = cell / 5, cx = cell % 5;
      ryLo = min(ryLo, max(cy - 1, 0)); ryHi = max(ryHi, min(cy + 1, 4));
      rxLo = min(rxLo, max(cx - 1, 0)); rxHi = max(rxHi, min(cx + 1, 4));
    }
  }
  for (int ry = ryLo; ry <= ryHi; ry++) {
    const int r0 = opp_starts[b * 32 + ry * 5 + rxLo];
    const int r1 = opp_starts[b * 32 + ry * 5 + rxHi + 1];
    for (int j = r0 + lane; j < r1; j += 64) {
      float4 o = opp[b * BN + j];
      #pragma unroll
      for (int i = 0; i < 4; i++) {
        float dx = me[i].x - o.x, dy = me[i].y - o.y;
        float d2 = fmaf(dx, dx, dy * dy);
        bool  c  = (d2 < T2) && (o.w != 0.f) && (me[i].w != 0.f);
        float t  = c ? fmaf(d2, -INV_EPS, o.z) : -3e30f;
        s[i] += __expf(t);
      }
    }
  }
  #pragma unroll
  for (int i = 0; i < 4; i++)
    for (int off = 32; off > 0; off >>= 1) s[i] += __shfl_xor(s[i], off);
  if (lane == 0) {
    const float Zf = (float)Zin[b];
    #pragma unroll
    for (int i = 0; i < 4; i++) {
      float ss  = s[i] + Zf;
      float val = (ss > 0.f) ? -logf(ss) : 1.0e9f;
      if (zero_invalid && me[i].w == 0.f) val = 0.f;
      own[rowb + i] = make_float4(me[i].x, me[i].y, val, me[i].w);
      if (val == 1.0e9f) atomicAdd(&Zout[b], 1);
    }
  }
}

// ------------------------------------------------- sparse attn @ feats ------
// MFMA v5: CHUNK-PAIRED persistent-queue version. Theory: k_out is bound by
// the ~950MB of redundant tile staging (6 chunks re-read each cell's box-row
// tiles; every sync variant r8-r10 ran at the same ~4 TB/s effective L2/L3
// staging BW). One item now = 64 targets (2 chunks), so each staged tile
// feeds 12 MFMA instead of 6: staging bytes HALVED. Items come from a global
// atomic queue (768 persistent blocks = 3/CU) to flatten the tail.
// Round structure = r10 (barrier-free per-wave depth-2 counted vmcnt(5),
// private s-slabs, per-wave channel-partitioned tiles).
#define BUFU   4352  // per-buffer u32: 4096 fB tile + 4 x 64 private s-slabs
#define NITEMS (BB * 25 * 3 * 6)   // b x cell x rsel x pair(64 tgt) = 1800

__global__ __launch_bounds__(256) void k_out(
    const unsigned* __restrict__ fB, const float4* __restrict__ t_sorted,
    const float4* __restrict__ s_sorted, const int* __restrict__ perm_t,
    const int* __restrict__ starts_t, const int* __restrict__ starts_s,
    int* __restrict__ qcnt, float* __restrict__ out) {
  __shared__ __align__(16) unsigned pool[3 * BUFU];  // 52.2KB; Dl overlays
  __shared__ float4 tL[64];
  __shared__ int qi;

  const int tid  = threadIdx.x;
  const int lane = tid & 63;
  const int w    = tid >> 6;
  const int kg   = lane >> 5;                // k-half: src kg*8 .. +7
  const int ln   = lane & 31;                // n(tm) for B/D, m(ch) for A

  for (;;) {
    if (tid == 0) qi = atomicAdd(qcnt, 1);
    __syncthreads();
    const int item = qi;
    __syncthreads();
    if (item >= NITEMS) break;
    // decode (uniform): b, cell, rsel, pair
    const int b    = item / 450;               // 450 = 25*3*6
    const int r1_  = item % 450;
    const int cell = r1_ / 18;
    const int r2_  = r1_ % 18;
    const int rsel = r2_ / 6, pair = r2_ % 6;
    const int cy = cell / 5, cx = cell % 5;
    const int ry = cy + rsel - 1;
    if (ry < 0 || ry > 4) continue;
    const int t0 = starts_t[b * 32 + cell], t1 = starts_t[b * 32 + cell + 1];
    const int base = t0 + pair * 64;
    if (base >= t1) continue;
    const int rx0 = max(cx - 1, 0), rx1 = min(cx + 1, 4);
    const int s0 = starts_s[b * 32 + ry * 5 + rx0];
    const int s1 = starts_s[b * 32 + ry * 5 + rx1 + 1];
    if (s0 >= s1) continue;
    const int nt = min(64, t1 - base);

    if (tid < 64)
      tL[tid] = (tid < nt) ? t_sorted[b * BN + base + tid]
                           : make_float4(0.f, 0.f, 0.f, 0.f);   // tv=0 -> attn 0
    __syncthreads();
    const float4 t4a0 = tL[ln];                // chunk0 target row
    const float4 t4a1 = tL[32 + ln];           // chunk1 target row
    const int sB = b * BN;
    const int blk0 = s0 >> 4;
    const int nBlk = ((s1 + 15) >> 4) - blk0;

    const unsigned* fBb = fB + (((size_t)b) << 20);
    auto ISSUE = [&](int t, int bufI) {        // 5 DMAs/wave, partitioned chans
      const unsigned* g = fBb + ((size_t)t << 12);
      unsigned* lb = pool + bufI * BUFU;
      #pragma unroll
      for (int q = 0; q < 4; q++)
        dma16(g + (w * 4 + q) * 256 + lane * 4, (void*)(lb + (w * 4 + q) * 256));
      dma4((const char*)s_sorted + ((size_t)(sB + t * 16) << 4) + lane * 4,
           (void*)(lb + 4096 + w * 64));
    };
    ISSUE(blk0, 0);
    ISSUE(blk0 + min(1, nBlk - 1), 1);

    f32x16 a00, a01, a10, a11;                 // acc[chunk][mt]
    #pragma unroll
    for (int i = 0; i < 16; i++) { a00[i] = 0.f; a01[i] = 0.f; a10[i] = 0.f; a11[i] = 0.f; }

    int cur = 0;
    for (int r = 0; r < nBlk; r++) {
      asm volatile("s_waitcnt vmcnt(5)" ::: "memory");     // own slot r landed
      __builtin_amdgcn_sched_barrier(0);                   // rule #18 fence
      ISSUE(blk0 + min(r + 2, nBlk - 1), cur == 0 ? 2 : cur - 1);
      const unsigned* tile = pool + cur * BUFU;
      // ---- B fragments for BOTH chunks from the private s-slab -------------
      const int j0 = (blk0 + r) * 16 + kg * 8;
      unsigned ah0[8], al0[8], ah1[8], al1[8];
      #pragma unroll
      for (int e = 0; e < 8; e++) {
        float4 s4 = *(const float4*)(tile + 4096 + w * 64 + (kg * 8 + e) * 4);
        int j = j0 + e;
        bool inr = (j >= s0) && (j < s1) && (s4.w != 0.f);
        float dx0 = t4a0.x - s4.x, dy0 = t4a0.y - s4.y;
        float d20 = fmaf(dx0, dx0, dy0 * dy0);
        bool  c0  = inr && (d20 < T2) && (t4a0.w != 0.f);
        float a0  = c0 ? __expf(fmaf(d20, -INV_EPS, t4a0.z + s4.z)) : 0.f;
        unsigned ab0 = __float_as_uint(a0);
        unsigned hb0 = ab0 & 0xFFFF0000u;
        float alo0 = a0 - __uint_as_float(hb0);
        ah0[e] = ab0 >> 16; al0[e] = __float_as_uint(alo0) >> 16;
        float dx1 = t4a1.x - s4.x, dy1 = t4a1.y - s4.y;
        float d21 = fmaf(dx1, dx1, dy1 * dy1);
        bool  c1  = inr && (d21 < T2) && (t4a1.w != 0.f);
        float a1  = c1 ? __expf(fmaf(d21, -INV_EPS, t4a1.z + s4.z)) : 0.f;
        unsigned ab1 = __float_as_uint(a1);
        unsigned hb1 = ab1 & 0xFFFF0000u;
        float alo1 = a1 - __uint_as_float(hb1);
        ah1[e] = ab1 >> 16; al1[e] = __float_as_uint(alo1) >> 16;
      }
      union { unsigned u[4]; bf16x8 v; } BH0, BL0, BH1, BL1;
      #pragma unroll
      for (int i = 0; i < 4; i++) {
        BH0.u[i] = ah0[2*i] | (ah0[2*i+1] << 16);
        BL0.u[i] = al0[2*i] | (al0[2*i+1] << 16);
        BH1.u[i] = ah1[2*i] | (ah1[2*i+1] << 16);
        BL1.u[i] = al1[2*i] | (al1[2*i+1] << 16);
      }
      // ---- A fragments (shared by both chunks) + 12 MFMA -------------------
      #pragma unroll
      for (int mt = 0; mt < 2; mt++) {
        const int chl = w * 64 + mt * 32 + ln;
        const int xv  = (chl >> 1) & 3;
        const int g0  = ((kg << 1) | 0) ^ xv;
        const int g1  = ((kg << 1) | 1) ^ xv;
        union { uint4 q[2]; unsigned u[8]; } A;
        A.q[0] = *(const uint4*)(tile + chl * 16 + g0 * 4);
        A.q[1] = *(const uint4*)(tile + chl * 16 + g1 * 4);
        union { unsigned u[4]; bf16x8 v; } AH, AL;
        #pragma unroll
        for (int i = 0; i < 4; i++) {
          AH.u[i] = (A.u[2*i] >> 16)     | (A.u[2*i+1] & 0xFFFF0000u);
          AL.u[i] = (A.u[2*i] & 0xFFFFu) | (A.u[2*i+1] << 16);
        }
        if (mt == 0) {
          a00 = __builtin_amdgcn_mfma_f32_32x32x16_bf16(AH.v, BH0.v, a00, 0, 0, 0);
          a00 = __builtin_amdgcn_mfma_f32_32x32x16_bf16(AH.v, BL0.v, a00, 0, 0, 0);
          a00 = __builtin_amdgcn_mfma_f32_32x32x16_bf16(AL.v, BH0.v, a00, 0, 0, 0);
          a10 = __builtin_amdgcn_mfma_f32_32x32x16_bf16(AH.v, BH1.v, a10, 0, 0, 0);
          a10 = __builtin_amdgcn_mfma_f32_32x32x16_bf16(AH.v, BL1.v, a10, 0, 0, 0);
          a10 = __builtin_amdgcn_mfma_f32_32x32x16_bf16(AL.v, BH1.v, a10, 0, 0, 0);
        } else {
          a01 = __builtin_amdgcn_mfma_f32_32x32x16_bf16(AH.v, BH0.v, a01, 0, 0, 0);
          a01 = __builtin_amdgcn_mfma_f32_32x32x16_bf16(AH.v, BL0.v, a01, 0, 0, 0);
          a01 = __builtin_amdgcn_mfma_f32_32x32x16_bf16(AL.v, BH0.v, a01, 0, 0, 0);
          a11 = __builtin_amdgcn_mfma_f32_32x32x16_bf16(AH.v, BH1.v, a11, 0, 0, 0);
          a11 = __builtin_amdgcn_mfma_f32_32x32x16_bf16(AH.v, BL1.v, a11, 0, 0, 0);
          a11 = __builtin_amdgcn_mfma_f32_32x32x16_bf16(AL.v, BH1.v, a11, 0, 0, 0);
        }
      }
      cur = (cur == 2) ? 0 : cur + 1;
    }

    // ---- epilogue: drain, then per-chunk Dl bounce + atomic flush ----------
    asm volatile("s_waitcnt vmcnt(0)" ::: "memory");       // own in-flight DMAs
    __syncthreads();                           // all waves done with pool
    float* Dl = (float*)pool;
    #pragma unroll
    for (int c = 0; c < 2; c++) {
      #pragma unroll
      for (int mt = 0; mt < 2; mt++) {
        #pragma unroll
        for (int rg = 0; rg < 4; rg++) {       // regs rg*4..+3 -> rows 8rg+4kg..+3
          int chb = w * 64 + mt * 32 + 8 * rg + 4 * kg;
          float4 v;
          if (c == 0) {
            if (mt == 0) v = make_float4(a00[rg*4], a00[rg*4+1], a00[rg*4+2], a00[rg*4+3]);
            else         v = make_float4(a01[rg*4], a01[rg*4+1], a01[rg*4+2], a01[rg*4+3]);
          } else {
            if (mt == 0) v = make_float4(a10[rg*4], a10[rg*4+1], a10[rg*4+2], a10[rg*4+3]);
            else         v = make_float4(a11[rg*4], a11[rg*4+1], a11[rg*4+2], a11[rg*4+3]);
          }
          *(float4*)&Dl[ln * 268 + chb] = v;
        }
      }
      __syncthreads();
      {
        const int tmg = tid >> 5, chg = tid & 31;
        #pragma unroll
        for (int i = 0; i < 4; i++) {
          int tm = tmg * 4 + i;
          int gt = c * 32 + tm;
          if (gt < nt) {
            int row = perm_t[sB + base + gt];
            float* op = out + (((b << 12) + row) << 8) + chg * 4;
            float4 d0 = *(float4*)&Dl[tm * 268 + chg * 4];
            float4 d1 = *(float4*)&Dl[tm * 268 + 128 + chg * 4];
            atomicAdd(op + 0, d0.x); atomicAdd(op + 1, d0.y);
            atomicAdd(op + 2, d0.z); atomicAdd(op + 3, d0.w);
            atomicAdd(op + 128, d1.x); atomicAdd(op + 129, d1.y);
            atomicAdd(op + 130, d1.z); atomicAdd(op + 131, d1.w);
          }
        }
      }
      __syncthreads();                         // Dl free for next chunk / item
    }
  }
}

// ----------------------------------------------------------------- launch ---
extern "C" void kernel_launch(void* const* d_in, const int* in_sizes, int n_in,
                              void* d_out, int out_size, void* d_ws, size_t ws_size,
                              hipStream_t stream) {
  const float* feats = (const float*)d_in[0];   // [B,N,C] f32
  const float* slocs = (const float*)d_in[1];   // [B,N,2] f32
  const float* tlocs = (const float*)d_in[2];   // [B,M,2] f32
  const int*   smask = (const int*)d_in[3];     // [B,N] int32 (bool)
  const int*   tmask = (const int*)d_in[4];     // [B,M] int32 (bool)
  float* out = (float*)d_out;

  char* ws = (char*)d_ws;                       // ~660 KB + 16 MB fB
  int*    qcnt     = (int*)(ws);                //   work-queue counter
  int*    Zc       = (int*)(ws + 1024);         //   256 ints; slot 0 stays 0
  int*    starts_t = (int*)(ws + 2048);         //   512 B
  int*    starts_s = (int*)(ws + 2560);         //   512 B
  int*    perm_t   = (int*)(ws + 4096);         //   64 KB
  int*    perm_s   = (int*)(ws + 69632);        //   64 KB
  float4* s_sorted = (float4*)(ws + 135168);    //  256 KB (x,y,v,sv) cell-sorted
  float4* t_sorted = (float4*)(ws + 397312);    //  256 KB (x,y,u,tv) cell-sorted
  unsigned* fB     = (unsigned*)(ws + 663552);  // 16 MB packed feats tiles

  hipMemsetAsync(out, 0, (size_t)out_size * sizeof(float), stream);
  k_bin<<<8, 256, 0, stream>>>(tlocs, slocs, tmask, smask, Zc, qcnt,
                               starts_t, starts_s, perm_t, perm_s,
                               t_sorted, s_sorted);
  k_pack<<<1024, 256, 0, stream>>>(feats, perm_s, fB);
  for (int it = 0; it < 3; it++) {
    k_sink<<<1024, 256, 0, stream>>>(s_sorted, t_sorted, starts_s,
                                     Zc + (it == 0 ? 0 : (2 * it) * 4),
                                     Zc + (2 * it + 1) * 4, 0);
    k_sink<<<1024, 256, 0, stream>>>(t_sorted, s_sorted, starts_t,
                                     Zc + (2 * it + 1) * 4,
                                     Zc + (2 * it + 2) * 4, 1);
  }
  k_out<<<768, 256, 0, stream>>>(fB, t_sorted, s_sorted, perm_t,
                                 starts_t, starts_s, qcnt, out);
}